// Round 1
// baseline (869.692 us; speedup 1.0000x reference)
//
#include <hip/hip_runtime.h>
#include <math.h>

#define BB 4
#define SS 4096
#define DD 768
#define HH 64
#define MM (BB * SS)

// ---------------- QKV projection: [16384,768] @ [768,64] + bias, x3 ----------------
// Block: 256 threads, tile 64 rows x 64 cols, K-chunk 16, 4x4 register blocking.
__global__ __launch_bounds__(256) void qkv_proj_kernel(
    const float* __restrict__ X,
    const float* __restrict__ Wq, const float* __restrict__ bq,
    const float* __restrict__ Wk, const float* __restrict__ bk,
    const float* __restrict__ Wv, const float* __restrict__ bv,
    float* __restrict__ outQKV)
{
    const int tid = threadIdx.x;
    const int rowBase = blockIdx.x * 64;
    const int which = blockIdx.y;
    const float* W    = (which == 0) ? Wq : (which == 1) ? Wk : Wv;
    const float* bias = (which == 0) ? bq : (which == 1) ? bk : bv;
    float* out = outQKV + (size_t)which * MM * HH;

    __shared__ __align__(16) float Xs[64][20];   // 64x16 tile, pad to 20 (80B rows)
    __shared__ __align__(16) float Wss[16][68];  // 16x64 tile, pad to 68 (272B rows, 16B-aligned)

    const int tx = tid & 15;   // col group
    const int ty = tid >> 4;   // row group
    const int r0 = ty * 4;
    const int c0 = tx * 4;

    float acc[4][4] = {};

    for (int kb = 0; kb < DD / 16; ++kb) {
        const int kBase = kb * 16;
        // Stage X tile: 64 rows x 16 cols = 256 float4, one per thread.
        {
            const int r = tid >> 2, ch = tid & 3;
            float4 v = *reinterpret_cast<const float4*>(
                &X[(size_t)(rowBase + r) * DD + kBase + ch * 4]);
            Xs[r][ch * 4 + 0] = v.x; Xs[r][ch * 4 + 1] = v.y;
            Xs[r][ch * 4 + 2] = v.z; Xs[r][ch * 4 + 3] = v.w;
        }
        // Stage W tile: 16 rows x 64 cols = 256 float4, one per thread.
        {
            const int r = tid >> 4, ch = tid & 15;
            float4 v = *reinterpret_cast<const float4*>(
                &W[(size_t)(kBase + r) * HH + ch * 4]);
            Wss[r][ch * 4 + 0] = v.x; Wss[r][ch * 4 + 1] = v.y;
            Wss[r][ch * 4 + 2] = v.z; Wss[r][ch * 4 + 3] = v.w;
        }
        __syncthreads();

        #pragma unroll
        for (int kk = 0; kk < 16; ++kk) {
            float4 wv = *reinterpret_cast<const float4*>(&Wss[kk][c0]);
            float xv[4];
            #pragma unroll
            for (int i = 0; i < 4; ++i) xv[i] = Xs[r0 + i][kk];
            #pragma unroll
            for (int i = 0; i < 4; ++i) {
                acc[i][0] += xv[i] * wv.x;
                acc[i][1] += xv[i] * wv.y;
                acc[i][2] += xv[i] * wv.z;
                acc[i][3] += xv[i] * wv.w;
            }
        }
        __syncthreads();
    }

    #pragma unroll
    for (int i = 0; i < 4; ++i) {
        #pragma unroll
        for (int j = 0; j < 4; ++j) {
            out[(size_t)(rowBase + r0 + i) * HH + c0 + j] = acc[i][j] + bias[c0 + j];
        }
    }
}

// ---------------- Flash-style causal attention, fp32 ----------------
// Block: 256 threads = 4 waves; block handles 4 consecutive query rows.
// Wave w owns row q0+w; lane = one key (scores) / one output dim (PV).
__global__ __launch_bounds__(256) void attn_kernel(
    const float* __restrict__ Q, const float* __restrict__ K,
    const float* __restrict__ V, float* __restrict__ out)
{
    const int b = blockIdx.y;
    const int q0 = blockIdx.x * 4;
    const int w = threadIdx.x >> 6;
    const int lane = threadIdx.x & 63;
    const int q = q0 + w;
    const float* Qb = Q + (size_t)b * SS * HH;
    const float* Kb = K + (size_t)b * SS * HH;
    const float* Vb = V + (size_t)b * SS * HH;

    __shared__ float Ks[64][65];  // +1 pad: score reads are 2-way conflict (free)
    __shared__ float Vs[64][65];  // PV reads conflict-free (consecutive lanes)
    __shared__ float Pl[4][64];

    // Q row in registers (scale 1/sqrt(64)=0.125 folded in)
    float qreg[64];
    #pragma unroll
    for (int d = 0; d < 64; ++d) qreg[d] = Qb[(size_t)q * HH + d] * 0.125f;

    float m = -INFINITY, l = 0.f, acc = 0.f;
    // q0 % 64 <= 60, so (q0+3)/64 == q0/64 : loop bound uniform over the block.
    const int nkb = q0 / 64 + 1;

    for (int kb = 0; kb < nkb; ++kb) {
        const int k0 = kb * 64;
        __syncthreads();  // previous iteration's reads done before overwrite
        // Stage K,V 64x64 tiles: 1024 float4 each, 4 per thread per matrix.
        {
            const int tid = threadIdx.x;
            #pragma unroll
            for (int i = 0; i < 4; ++i) {
                const int idx = tid + i * 256;
                const int r = idx >> 4, ch = idx & 15;
                float4 kv = *reinterpret_cast<const float4*>(
                    &Kb[(size_t)(k0 + r) * HH + ch * 4]);
                Ks[r][ch * 4 + 0] = kv.x; Ks[r][ch * 4 + 1] = kv.y;
                Ks[r][ch * 4 + 2] = kv.z; Ks[r][ch * 4 + 3] = kv.w;
                float4 vv = *reinterpret_cast<const float4*>(
                    &Vb[(size_t)(k0 + r) * HH + ch * 4]);
                Vs[r][ch * 4 + 0] = vv.x; Vs[r][ch * 4 + 1] = vv.y;
                Vs[r][ch * 4 + 2] = vv.z; Vs[r][ch * 4 + 3] = vv.w;
            }
        }
        __syncthreads();

        // Score for this lane's key
        float s = 0.f;
        #pragma unroll
        for (int d = 0; d < 64; ++d) s += qreg[d] * Ks[lane][d];
        const int k = k0 + lane;
        const bool valid = (k <= q);
        s = valid ? s : -INFINITY;

        // Online softmax (wave-wide reductions over 64 lanes)
        float mx = s;
        #pragma unroll
        for (int off = 32; off > 0; off >>= 1) mx = fmaxf(mx, __shfl_xor(mx, off));
        const float mnew = fmaxf(m, mx);
        const float p = valid ? __expf(s - mnew) : 0.f;
        float ps = p;
        #pragma unroll
        for (int off = 32; off > 0; off >>= 1) ps += __shfl_xor(ps, off);
        const float corr = (m == -INFINITY) ? 0.f : __expf(m - mnew);
        l = l * corr + ps;
        acc *= corr;
        m = mnew;

        Pl[w][lane] = p;
        __syncthreads();  // make Pl visible (uniform control flow)

        // PV: lane owns output dim d=lane
        #pragma unroll
        for (int j = 0; j < 64; ++j) acc += Pl[w][j] * Vs[j][lane];
    }

    out[((size_t)b * SS + q) * HH + lane] = acc / l;
}

extern "C" void kernel_launch(void* const* d_in, const int* in_sizes, int n_in,
                              void* d_out, int out_size, void* d_ws, size_t ws_size,
                              hipStream_t stream)
{
    const float* X  = (const float*)d_in[0];
    const float* Wq = (const float*)d_in[1];
    const float* bq = (const float*)d_in[2];
    const float* Wk = (const float*)d_in[3];
    const float* bk = (const float*)d_in[4];
    const float* Wv = (const float*)d_in[5];
    const float* bv = (const float*)d_in[6];

    float* qkv = (float*)d_ws;  // Q,K,V fp32: 3 * 16384 * 64 * 4B = 12 MB
    float* Qf = qkv;
    float* Kf = qkv + (size_t)MM * HH;
    float* Vf = qkv + 2 * (size_t)MM * HH;

    dim3 gp(MM / 64, 3);
    qkv_proj_kernel<<<gp, 256, 0, stream>>>(X, Wq, bq, Wk, bk, Wv, bv, qkv);

    dim3 ga(SS / 4, BB);
    attn_kernel<<<ga, 256, 0, stream>>>(Qf, Kf, Vf, (float*)d_out);
}

// Round 2
// 159.626 us; speedup vs baseline: 5.4483x; 5.4483x over previous
//
#include <hip/hip_runtime.h>
#include <math.h>

#define BB 4
#define SS 4096
#define DD 768
#define HH 64
#define MM (BB * SS)

typedef __attribute__((ext_vector_type(8))) short bf16x8;
typedef __attribute__((ext_vector_type(4))) float f32x4;

__device__ inline unsigned short f2bf(float f) {
    union { float f; unsigned u; } x; x.f = f;
    unsigned r = x.u + 0x7fffu + ((x.u >> 16) & 1u);
    return (unsigned short)(r >> 16);
}

// ---------------- QKV projection (fp32 compute) -> bf16 Q(scaled), K, V^T ----------------
__global__ __launch_bounds__(256) void qkv_proj_kernel(
    const float* __restrict__ X,
    const float* __restrict__ Wq, const float* __restrict__ bq,
    const float* __restrict__ Wk, const float* __restrict__ bk,
    const float* __restrict__ Wv, const float* __restrict__ bv,
    unsigned short* __restrict__ Qb, unsigned short* __restrict__ Kb,
    unsigned short* __restrict__ Vt)
{
    const int tid = threadIdx.x;
    const int rowBase = blockIdx.x * 64;
    const int which = blockIdx.y;
    const float* W    = (which == 0) ? Wq : (which == 1) ? Wk : Wv;
    const float* bias = (which == 0) ? bq : (which == 1) ? bk : bv;

    __shared__ __align__(16) float Xs[64][20];
    __shared__ __align__(16) float Wss[16][68];

    const int tx = tid & 15;
    const int ty = tid >> 4;
    const int r0 = ty * 4;
    const int c0 = tx * 4;

    float acc[4][4] = {};

    for (int kb = 0; kb < DD / 16; ++kb) {
        const int kBase = kb * 16;
        {
            const int r = tid >> 2, ch = tid & 3;
            float4 v = *reinterpret_cast<const float4*>(
                &X[(size_t)(rowBase + r) * DD + kBase + ch * 4]);
            Xs[r][ch * 4 + 0] = v.x; Xs[r][ch * 4 + 1] = v.y;
            Xs[r][ch * 4 + 2] = v.z; Xs[r][ch * 4 + 3] = v.w;
        }
        {
            const int r = tid >> 4, ch = tid & 15;
            float4 v = *reinterpret_cast<const float4*>(
                &W[(size_t)(kBase + r) * HH + ch * 4]);
            Wss[r][ch * 4 + 0] = v.x; Wss[r][ch * 4 + 1] = v.y;
            Wss[r][ch * 4 + 2] = v.z; Wss[r][ch * 4 + 3] = v.w;
        }
        __syncthreads();

        #pragma unroll
        for (int kk = 0; kk < 16; ++kk) {
            float4 wv = *reinterpret_cast<const float4*>(&Wss[kk][c0]);
            float xv[4];
            #pragma unroll
            for (int i = 0; i < 4; ++i) xv[i] = Xs[r0 + i][kk];
            #pragma unroll
            for (int i = 0; i < 4; ++i) {
                acc[i][0] += xv[i] * wv.x;
                acc[i][1] += xv[i] * wv.y;
                acc[i][2] += xv[i] * wv.z;
                acc[i][3] += xv[i] * wv.w;
            }
        }
        __syncthreads();
    }

    if (which == 0) {
        #pragma unroll
        for (int i = 0; i < 4; ++i) {
            ushort4 pk;
            pk.x = f2bf((acc[i][0] + bias[c0 + 0]) * 0.125f);
            pk.y = f2bf((acc[i][1] + bias[c0 + 1]) * 0.125f);
            pk.z = f2bf((acc[i][2] + bias[c0 + 2]) * 0.125f);
            pk.w = f2bf((acc[i][3] + bias[c0 + 3]) * 0.125f);
            *reinterpret_cast<ushort4*>(&Qb[(size_t)(rowBase + r0 + i) * HH + c0]) = pk;
        }
    } else if (which == 1) {
        #pragma unroll
        for (int i = 0; i < 4; ++i) {
            ushort4 pk;
            pk.x = f2bf(acc[i][0] + bias[c0 + 0]);
            pk.y = f2bf(acc[i][1] + bias[c0 + 1]);
            pk.z = f2bf(acc[i][2] + bias[c0 + 2]);
            pk.w = f2bf(acc[i][3] + bias[c0 + 3]);
            *reinterpret_cast<ushort4*>(&Kb[(size_t)(rowBase + r0 + i) * HH + c0]) = pk;
        }
    } else {
        const int bb = rowBase >> 12;
        #pragma unroll
        for (int i = 0; i < 4; ++i) {
            const int s = (rowBase + r0 + i) & (SS - 1);
            #pragma unroll
            for (int j = 0; j < 4; ++j) {
                Vt[((size_t)bb * HH + c0 + j) * SS + s] = f2bf(acc[i][j] + bias[c0 + j]);
            }
        }
    }
}

// ---------------- MFMA flash attention ----------------
// Block = 512 threads (8 waves) per 64-row q-block. Waves 0-3: even KV tiles,
// waves 4-7: odd KV tiles. In-LDS flash combine at the end.
#define KVB 64
#define KP 72   // K/V/P LDS pitch (bf16 elems); makes ds_read_b128 bank-even

union SMemU {
    struct { unsigned short K[2][64][KP]; unsigned short V[2][64][KP]; } st; // 36864 B
    struct { float O[4][64][17]; float ml[4][64][8]; } cb;                   // 25600 B
};

__global__ __launch_bounds__(512) void attn_kernel(
    const unsigned short* __restrict__ Qg, const unsigned short* __restrict__ Kg,
    const unsigned short* __restrict__ Vtg, float* __restrict__ out)
{
    __shared__ SMemU sm;
    __shared__ unsigned short Pl[8][16][KP];   // per-wave P tile (q-local x key-local)

    const int tid = threadIdx.x;
    const int b  = blockIdx.y;
    const int qb = blockIdx.x;
    const int q0 = qb * 64;
    const int w   = tid >> 6;
    const int g   = w >> 2;         // tile-parity group
    const int wq  = w & 3;          // which 16-row strip
    const int lane = tid & 63;
    const int lhi = lane >> 4, llo = lane & 15;
    const int qw0 = q0 + wq * 16;

    // Q fragments in registers: A[row=llo][k=8*lhi+j], two d-halves
    bf16x8 qf0, qf1;
    {
        const unsigned short* qrow = Qg + ((size_t)b * SS + qw0 + llo) * HH + lhi * 8;
        qf0 = *reinterpret_cast<const bf16x8*>(qrow);
        qf1 = *reinterpret_cast<const bf16x8*>(qrow + 32);
    }

    float m[4] = {-INFINITY, -INFINITY, -INFINITY, -INFINITY};
    float l[4] = {0.f, 0.f, 0.f, 0.f};
    f32x4 acc_o[4] = {{0,0,0,0},{0,0,0,0},{0,0,0,0},{0,0,0,0}};

    const int ntiles = qb + 1;
    const int npairs = (ntiles + 1) >> 1;

    const unsigned short* Kbase = Kg  + (size_t)b * SS * HH;
    const unsigned short* Vbase = Vtg + (size_t)b * HH * SS;

    const int sr = tid >> 3;         // staging row 0..63
    const int sc = (tid & 7) * 8;    // staging col 0..56

    for (int jp = 0; jp < npairs; ++jp) {
        __syncthreads();
        {
            const int t0k = (2 * jp) * KVB;
            *reinterpret_cast<bf16x8*>(&sm.st.K[0][sr][sc]) =
                *reinterpret_cast<const bf16x8*>(&Kbase[(size_t)(t0k + sr) * HH + sc]);
            *reinterpret_cast<bf16x8*>(&sm.st.V[0][sr][sc]) =
                *reinterpret_cast<const bf16x8*>(&Vbase[(size_t)sr * SS + t0k + sc]);
            const int t1 = 2 * jp + 1;
            if (t1 < ntiles) {
                const int t1k = t1 * KVB;
                *reinterpret_cast<bf16x8*>(&sm.st.K[1][sr][sc]) =
                    *reinterpret_cast<const bf16x8*>(&Kbase[(size_t)(t1k + sr) * HH + sc]);
                *reinterpret_cast<bf16x8*>(&sm.st.V[1][sr][sc]) =
                    *reinterpret_cast<const bf16x8*>(&Vbase[(size_t)sr * SS + t1k + sc]);
            }
        }
        __syncthreads();

        const int t = 2 * jp + g;
        if (t < ntiles) {
            const int k0 = t * KVB;
            const unsigned short (&Ks)[64][KP] = sm.st.K[g];
            const unsigned short (&Vs)[64][KP] = sm.st.V[g];

            // ---- scores: S = Q K^T (pre-scaled Q) ----
            f32x4 sacc[4] = {{0,0,0,0},{0,0,0,0},{0,0,0,0},{0,0,0,0}};
            #pragma unroll
            for (int kt = 0; kt < 4; ++kt) {
                bf16x8 kfa = *reinterpret_cast<const bf16x8*>(&Ks[kt * 16 + llo][lhi * 8]);
                bf16x8 kfb = *reinterpret_cast<const bf16x8*>(&Ks[kt * 16 + llo][32 + lhi * 8]);
                sacc[kt] = __builtin_amdgcn_mfma_f32_16x16x32_bf16(qf0, kfa, sacc[kt], 0, 0, 0);
                sacc[kt] = __builtin_amdgcn_mfma_f32_16x16x32_bf16(qf1, kfb, sacc[kt], 0, 0, 0);
            }

            // ---- causal mask (only needed near/above diagonal) ----
            if (k0 + KVB - 1 > qw0) {
                #pragma unroll
                for (int kt = 0; kt < 4; ++kt) {
                    const int k = k0 + kt * 16 + llo;
                    #pragma unroll
                    for (int r = 0; r < 4; ++r) {
                        const int q = qw0 + lhi * 4 + r;
                        if (k > q) sacc[kt][r] = -INFINITY;
                    }
                }
            }

            // ---- online softmax per row ----
            float p[4][4];
            #pragma unroll
            for (int r = 0; r < 4; ++r) {
                float mx = fmaxf(fmaxf(sacc[0][r], sacc[1][r]), fmaxf(sacc[2][r], sacc[3][r]));
                mx = fmaxf(mx, __shfl_xor(mx, 1));
                mx = fmaxf(mx, __shfl_xor(mx, 2));
                mx = fmaxf(mx, __shfl_xor(mx, 4));
                mx = fmaxf(mx, __shfl_xor(mx, 8));
                const float mn = fmaxf(m[r], mx);
                const float corr = __expf(m[r] - mn);
                float ps = 0.f;
                #pragma unroll
                for (int kt = 0; kt < 4; ++kt) { p[kt][r] = __expf(sacc[kt][r] - mn); ps += p[kt][r]; }
                ps += __shfl_xor(ps, 1);
                ps += __shfl_xor(ps, 2);
                ps += __shfl_xor(ps, 4);
                ps += __shfl_xor(ps, 8);
                l[r] = l[r] * corr + ps;
                m[r] = mn;
                #pragma unroll
                for (int dt = 0; dt < 4; ++dt) acc_o[dt][r] *= corr;
            }

            // ---- P -> LDS (per-wave; same-wave readback, no barrier) ----
            #pragma unroll
            for (int kt = 0; kt < 4; ++kt)
                #pragma unroll
                for (int r = 0; r < 4; ++r)
                    Pl[w][lhi * 4 + r][kt * 16 + llo] = f2bf(p[kt][r]);

            bf16x8 pf0 = *reinterpret_cast<const bf16x8*>(&Pl[w][llo][lhi * 8]);
            bf16x8 pf1 = *reinterpret_cast<const bf16x8*>(&Pl[w][llo][32 + lhi * 8]);

            // ---- O += P V ----
            #pragma unroll
            for (int dt = 0; dt < 4; ++dt) {
                bf16x8 vfa = *reinterpret_cast<const bf16x8*>(&Vs[dt * 16 + llo][lhi * 8]);
                bf16x8 vfb = *reinterpret_cast<const bf16x8*>(&Vs[dt * 16 + llo][32 + lhi * 8]);
                acc_o[dt] = __builtin_amdgcn_mfma_f32_16x16x32_bf16(pf0, vfa, acc_o[dt], 0, 0, 0);
                acc_o[dt] = __builtin_amdgcn_mfma_f32_16x16x32_bf16(pf1, vfb, acc_o[dt], 0, 0, 0);
            }
        }
    }

    // ---- flash combine of even/odd partials via LDS ----
    __syncthreads();   // all reads of st done before aliasing writes
    if (g == 1) {
        #pragma unroll
        for (int dt = 0; dt < 4; ++dt)
            #pragma unroll
            for (int r = 0; r < 4; ++r)
                sm.cb.O[wq][lane][dt * 4 + r] = acc_o[dt][r];
        #pragma unroll
        for (int r = 0; r < 4; ++r) {
            sm.cb.ml[wq][lane][r] = m[r];
            sm.cb.ml[wq][lane][4 + r] = l[r];
        }
    }
    __syncthreads();
    if (g == 0) {
        const float* O2  = sm.cb.O[wq][lane];
        const float* ml2 = sm.cb.ml[wq][lane];
        #pragma unroll
        for (int r = 0; r < 4; ++r) {
            const float m2 = ml2[r], l2 = ml2[4 + r];
            const float M  = fmaxf(m[r], m2);
            const float a1 = __expf(m[r] - M);
            const float a2 = __expf(m2 - M);
            const float L  = l[r] * a1 + l2 * a2;
            const float invL = 1.f / L;
            const size_t orow = ((size_t)b * SS + qw0 + lhi * 4 + r) * HH;
            #pragma unroll
            for (int dt = 0; dt < 4; ++dt) {
                const float o = acc_o[dt][r] * a1 + O2[dt * 4 + r] * a2;
                out[orow + dt * 16 + llo] = o * invL;
            }
        }
    }
}

extern "C" void kernel_launch(void* const* d_in, const int* in_sizes, int n_in,
                              void* d_out, int out_size, void* d_ws, size_t ws_size,
                              hipStream_t stream)
{
    const float* X  = (const float*)d_in[0];
    const float* Wq = (const float*)d_in[1];
    const float* bq = (const float*)d_in[2];
    const float* Wk = (const float*)d_in[3];
    const float* bk = (const float*)d_in[4];
    const float* Wv = (const float*)d_in[5];
    const float* bv = (const float*)d_in[6];

    unsigned short* Qb = (unsigned short*)d_ws;                       // 2 MB
    unsigned short* Kb = Qb + (size_t)MM * HH;                        // 2 MB
    unsigned short* Vt = Kb + (size_t)MM * HH;                        // 2 MB (transposed)

    dim3 gp(MM / 64, 3);
    qkv_proj_kernel<<<gp, 256, 0, stream>>>(X, Wq, bq, Wk, bk, Wv, bv, Qb, Kb, Vt);

    dim3 ga(SS / 64, BB);
    attn_kernel<<<ga, 512, 0, stream>>>(Qb, Kb, Vt, (float*)d_out);
}

// Round 3
// 100.959 us; speedup vs baseline: 8.6143x; 1.5811x over previous
//
#include <hip/hip_runtime.h>
#include <math.h>

#define BB 4
#define SS 4096
#define DD 768
#define HH 64
#define MM (BB * SS)

typedef __attribute__((ext_vector_type(8))) short bf16x8;
typedef __attribute__((ext_vector_type(4))) float f32x4;

__device__ inline unsigned short f2bf(float f) {
    union { float f; unsigned u; } x; x.f = f;
    unsigned r = x.u + 0x7fffu + ((x.u >> 16) & 1u);
    return (unsigned short)(r >> 16);
}

// ---------------- One-time weight transpose: Wq|Wk|Wv [768,64] fp32 -> Wt [192][768] bf16 ----------------
// grid (12 k-tiles, 3 sel), 256 threads. Wt[n][k] = W_sel[k][n-sel*64].
__global__ __launch_bounds__(256) void wt_kernel(
    const float* __restrict__ Wq, const float* __restrict__ Wk, const float* __restrict__ Wv,
    unsigned short* __restrict__ Wt)
{
    const int kt = blockIdx.x;       // k-tile of 64
    const int sel = blockIdx.y;      // 0=Q,1=K,2=V
    const int k0 = kt * 64;
    const float* W = (sel == 0) ? Wq : (sel == 1) ? Wk : Wv;
    __shared__ float Ws[64][68];
    const int t = threadIdx.x;
    // load 64x64 fp32 tile (coalesced)
    #pragma unroll
    for (int j = 0; j < 4; ++j) {
        const int fl = t + j * 256;          // 0..1023 float4s
        const int row = fl >> 4, c4 = (fl & 15) * 4;
        float4 v = *reinterpret_cast<const float4*>(&W[(size_t)(k0 + row) * HH + c4]);
        Ws[row][c4 + 0] = v.x; Ws[row][c4 + 1] = v.y;
        Ws[row][c4 + 2] = v.z; Ws[row][c4 + 3] = v.w;
    }
    __syncthreads();
    // write transposed bf16: thread -> (n = t>>2, k-chunk of 16)
    const int n = t >> 2;
    const int c8 = (t & 3) * 16;
    unsigned short tmp[16];
    #pragma unroll
    for (int j = 0; j < 16; ++j) tmp[j] = f2bf(Ws[c8 + j][n]);
    unsigned short* dst = &Wt[((size_t)sel * 64 + n) * DD + k0 + c8];
    *reinterpret_cast<bf16x8*>(dst)     = *reinterpret_cast<bf16x8*>(&tmp[0]);
    *reinterpret_cast<bf16x8*>(dst + 8) = *reinterpret_cast<bf16x8*>(&tmp[8]);
}

// ---------------- QKV projection via MFMA: [16384,768]x[768,192] ----------------
// 512 blocks x 512 threads. Block tile: M=32, N=192, BK=64, 12 K-iters.
// Waves: ms = w&1 (16-row strip), nq = w>>1 (48-col quarter = 3 n-tiles).
#define PP 72   // LDS pitch (bf16) keeps b128 16B-aligned
__global__ __launch_bounds__(512) void qkv_proj_kernel(
    const float* __restrict__ X, const unsigned short* __restrict__ Wt,
    const float* __restrict__ bq, const float* __restrict__ bk, const float* __restrict__ bv,
    unsigned short* __restrict__ Qb, unsigned short* __restrict__ Kb,
    unsigned short* __restrict__ Vt)
{
    __shared__ unsigned short Alds[32][PP];
    __shared__ unsigned short Blds[192][PP];

    const int tid = threadIdx.x;
    const int rowBase = blockIdx.x * 32;
    const int w = tid >> 6;
    const int ms = w & 1;
    const int nq = w >> 1;
    const int lane = tid & 63;
    const int lhi = lane >> 4, llo = lane & 15;

    f32x4 acc[3] = {{0,0,0,0},{0,0,0,0},{0,0,0,0}};

    for (int kb = 0; kb < DD / 64; ++kb) {
        const int kBase = kb * 64;
        __syncthreads();
        // stage A: 32x64 fp32 -> bf16 (1 float4/thread)
        {
            const int row = tid >> 4, c4 = (tid & 15) * 4;
            float4 v = *reinterpret_cast<const float4*>(
                &X[(size_t)(rowBase + row) * DD + kBase + c4]);
            ushort4 pk;
            pk.x = f2bf(v.x); pk.y = f2bf(v.y); pk.z = f2bf(v.z); pk.w = f2bf(v.w);
            *reinterpret_cast<ushort4*>(&Alds[row][c4]) = pk;
        }
        // stage B: 192x64 bf16 (3 bf16x8/thread)
        #pragma unroll
        for (int i = 0; i < 3; ++i) {
            const int u = tid + i * 512;     // 0..1535
            const int n = u >> 3, c8 = (u & 7) * 8;
            *reinterpret_cast<bf16x8*>(&Blds[n][c8]) =
                *reinterpret_cast<const bf16x8*>(&Wt[(size_t)n * DD + kBase + c8]);
        }
        __syncthreads();

        #pragma unroll
        for (int kk = 0; kk < 2; ++kk) {
            const int aoff = kk * 32 + lhi * 8;
            bf16x8 af = *reinterpret_cast<const bf16x8*>(&Alds[ms * 16 + llo][aoff]);
            #pragma unroll
            for (int nt = 0; nt < 3; ++nt) {
                bf16x8 bf = *reinterpret_cast<const bf16x8*>(&Blds[nq * 48 + nt * 16 + llo][aoff]);
                acc[nt] = __builtin_amdgcn_mfma_f32_16x16x32_bf16(af, bf, acc[nt], 0, 0, 0);
            }
        }
    }

    // epilogue: bias + scale/store per n-tile
    #pragma unroll
    for (int nt = 0; nt < 3; ++nt) {
        const int n = nq * 48 + nt * 16 + llo;
        const int sel = n >> 6;
        const int nn = n & 63;
        const float bias = (sel == 0) ? bq[nn] : (sel == 1) ? bk[nn] : bv[nn];
        #pragma unroll
        for (int r = 0; r < 4; ++r) {
            const int row = rowBase + ms * 16 + lhi * 4 + r;
            const float val = acc[nt][r] + bias;
            if (sel == 0) {
                Qb[(size_t)row * HH + nn] = f2bf(val * 0.125f);
            } else if (sel == 1) {
                Kb[(size_t)row * HH + nn] = f2bf(val);
            } else {
                const int bb = row >> 12;
                const int s = row & (SS - 1);
                Vt[((size_t)bb * HH + nn) * SS + s] = f2bf(val);
            }
        }
    }
}

// ---------------- MFMA flash attention, 4 KV groups ----------------
// 1024 threads = 16 waves: group g = w>>2 takes KV tiles g, g+4, ...;
// wq = w&3 is the 16-row q strip. 4-way flash combine in LDS at the end.
#define KP 72

union SMemA {
    struct { unsigned short K[4][64][KP]; unsigned short V[4][64][KP]; } st; // 73728 B
    struct { float O[3][64][68]; float ml[3][64][2]; } cb;                    // 53760 B
};

__global__ __launch_bounds__(1024) void attn_kernel(
    const unsigned short* __restrict__ Qg, const unsigned short* __restrict__ Kg,
    const unsigned short* __restrict__ Vtg, float* __restrict__ out)
{
    __shared__ SMemA sm;
    __shared__ unsigned short Pl[16][16][KP];   // 36864 B

    const int tid = threadIdx.x;
    const int b  = blockIdx.y;
    const int qb = blockIdx.x;
    const int q0 = qb * 64;
    const int w   = tid >> 6;
    const int g   = w >> 2;
    const int wq  = w & 3;
    const int lane = tid & 63;
    const int lhi = lane >> 4, llo = lane & 15;
    const int qw0 = q0 + wq * 16;

    const unsigned short* Kbase = Kg  + (size_t)b * SS * HH;
    const unsigned short* Vbase = Vtg + (size_t)b * HH * SS;

    bf16x8 qf0, qf1;
    {
        const unsigned short* qrow = Qg + ((size_t)b * SS + qw0 + llo) * HH + lhi * 8;
        qf0 = *reinterpret_cast<const bf16x8*>(qrow);
        qf1 = *reinterpret_cast<const bf16x8*>(qrow + 32);
    }

    float m[4] = {-INFINITY, -INFINITY, -INFINITY, -INFINITY};
    float l[4] = {0.f, 0.f, 0.f, 0.f};
    f32x4 acc_o[4] = {{0,0,0,0},{0,0,0,0},{0,0,0,0},{0,0,0,0}};

    const int ntiles = qb + 1;
    const int nsteps = (ntiles + 3) >> 2;

    for (int stp = 0; stp < nsteps; ++stp) {
        const int base = stp * 4;
        __syncthreads();
        // stage up to 4 K tiles + 4 V tiles (64 KB); wave-uniform guards
        #pragma unroll
        for (int i = 0; i < 4; ++i) {
            const int u = tid + i * 1024;       // 0..4095 vec8 units
            const int selv = u >> 9;            // 0..7
            const int gi = selv & 3;
            const int t = base + gi;
            if (t < ntiles) {
                const int within = u & 511;
                const int row = within >> 3, c8 = (within & 7) * 8;
                if (selv < 4) {
                    *reinterpret_cast<bf16x8*>(&sm.st.K[gi][row][c8]) =
                        *reinterpret_cast<const bf16x8*>(&Kbase[(size_t)(t * 64 + row) * HH + c8]);
                } else {
                    *reinterpret_cast<bf16x8*>(&sm.st.V[gi][row][c8]) =
                        *reinterpret_cast<const bf16x8*>(&Vbase[(size_t)row * SS + t * 64 + c8]);
                }
            }
        }
        __syncthreads();

        const int lt = base + g;
        if (lt < ntiles) {
            const int k0 = lt * 64;
            const unsigned short (&Ks)[64][KP] = sm.st.K[g];
            const unsigned short (&Vs)[64][KP] = sm.st.V[g];

            // ---- S = Q K^T ----
            f32x4 sacc[4] = {{0,0,0,0},{0,0,0,0},{0,0,0,0},{0,0,0,0}};
            #pragma unroll
            for (int kt = 0; kt < 4; ++kt) {
                bf16x8 kfa = *reinterpret_cast<const bf16x8*>(&Ks[kt * 16 + llo][lhi * 8]);
                bf16x8 kfb = *reinterpret_cast<const bf16x8*>(&Ks[kt * 16 + llo][32 + lhi * 8]);
                sacc[kt] = __builtin_amdgcn_mfma_f32_16x16x32_bf16(qf0, kfa, sacc[kt], 0, 0, 0);
                sacc[kt] = __builtin_amdgcn_mfma_f32_16x16x32_bf16(qf1, kfb, sacc[kt], 0, 0, 0);
            }

            // ---- causal mask ----
            if (k0 + 63 > qw0) {
                #pragma unroll
                for (int kt = 0; kt < 4; ++kt) {
                    const int k = k0 + kt * 16 + llo;
                    #pragma unroll
                    for (int r = 0; r < 4; ++r) {
                        const int q = qw0 + lhi * 4 + r;
                        if (k > q) sacc[kt][r] = -INFINITY;
                    }
                }
            }

            // ---- online softmax ----
            float p[4][4];
            #pragma unroll
            for (int r = 0; r < 4; ++r) {
                float mx = fmaxf(fmaxf(sacc[0][r], sacc[1][r]), fmaxf(sacc[2][r], sacc[3][r]));
                mx = fmaxf(mx, __shfl_xor(mx, 1));
                mx = fmaxf(mx, __shfl_xor(mx, 2));
                mx = fmaxf(mx, __shfl_xor(mx, 4));
                mx = fmaxf(mx, __shfl_xor(mx, 8));
                const float mn = fmaxf(m[r], mx);
                const float corr = __expf(m[r] - mn);
                float ps = 0.f;
                #pragma unroll
                for (int kt = 0; kt < 4; ++kt) { p[kt][r] = __expf(sacc[kt][r] - mn); ps += p[kt][r]; }
                ps += __shfl_xor(ps, 1);
                ps += __shfl_xor(ps, 2);
                ps += __shfl_xor(ps, 4);
                ps += __shfl_xor(ps, 8);
                l[r] = l[r] * corr + ps;
                m[r] = mn;
                #pragma unroll
                for (int dt = 0; dt < 4; ++dt) acc_o[dt][r] *= corr;
            }

            // ---- P -> LDS (same-wave roundtrip) ----
            #pragma unroll
            for (int kt = 0; kt < 4; ++kt)
                #pragma unroll
                for (int r = 0; r < 4; ++r)
                    Pl[w][lhi * 4 + r][kt * 16 + llo] = f2bf(p[kt][r]);

            bf16x8 pf0 = *reinterpret_cast<const bf16x8*>(&Pl[w][llo][lhi * 8]);
            bf16x8 pf1 = *reinterpret_cast<const bf16x8*>(&Pl[w][llo][32 + lhi * 8]);

            // ---- O += P V ----
            #pragma unroll
            for (int dt = 0; dt < 4; ++dt) {
                bf16x8 vfa = *reinterpret_cast<const bf16x8*>(&Vs[dt * 16 + llo][lhi * 8]);
                bf16x8 vfb = *reinterpret_cast<const bf16x8*>(&Vs[dt * 16 + llo][32 + lhi * 8]);
                acc_o[dt] = __builtin_amdgcn_mfma_f32_16x16x32_bf16(pf0, vfa, acc_o[dt], 0, 0, 0);
                acc_o[dt] = __builtin_amdgcn_mfma_f32_16x16x32_bf16(pf1, vfb, acc_o[dt], 0, 0, 0);
            }
        }
    }

    // ---- 4-way flash combine ----
    __syncthreads();
    if (g > 0) {
        #pragma unroll
        for (int dt = 0; dt < 4; ++dt)
            #pragma unroll
            for (int r = 0; r < 4; ++r)
                sm.cb.O[g - 1][wq * 16 + lhi * 4 + r][dt * 16 + llo] = acc_o[dt][r];
        if (llo == 0) {
            #pragma unroll
            for (int r = 0; r < 4; ++r) {
                sm.cb.ml[g - 1][wq * 16 + lhi * 4 + r][0] = m[r];
                sm.cb.ml[g - 1][wq * 16 + lhi * 4 + r][1] = l[r];
            }
        }
    }
    __syncthreads();
    if (g == 0) {
        #pragma unroll
        for (int r = 0; r < 4; ++r) {
            const int row = wq * 16 + lhi * 4 + r;
            float mg[3], lg[3];
            #pragma unroll
            for (int j = 0; j < 3; ++j) { mg[j] = sm.cb.ml[j][row][0]; lg[j] = sm.cb.ml[j][row][1]; }
            float M = fmaxf(fmaxf(m[r], mg[0]), fmaxf(mg[1], mg[2]));
            const float a0 = __expf(m[r] - M);
            float ag[3];
            float L = l[r] * a0;
            #pragma unroll
            for (int j = 0; j < 3; ++j) { ag[j] = __expf(mg[j] - M); L += lg[j] * ag[j]; }
            const float invL = 1.f / L;
            const size_t orow = ((size_t)b * SS + q0 + row) * HH;
            #pragma unroll
            for (int dt = 0; dt < 4; ++dt) {
                float o = acc_o[dt][r] * a0;
                #pragma unroll
                for (int j = 0; j < 3; ++j) o += sm.cb.O[j][row][dt * 16 + llo] * ag[j];
                out[orow + dt * 16 + llo] = o * invL;
            }
        }
    }
}

extern "C" void kernel_launch(void* const* d_in, const int* in_sizes, int n_in,
                              void* d_out, int out_size, void* d_ws, size_t ws_size,
                              hipStream_t stream)
{
    const float* X  = (const float*)d_in[0];
    const float* Wq = (const float*)d_in[1];
    const float* bq = (const float*)d_in[2];
    const float* Wk = (const float*)d_in[3];
    const float* bk = (const float*)d_in[4];
    const float* Wv = (const float*)d_in[5];
    const float* bv = (const float*)d_in[6];

    unsigned short* Qb = (unsigned short*)d_ws;          // 2 MB
    unsigned short* Kb = Qb + (size_t)MM * HH;           // 2 MB
    unsigned short* Vt = Kb + (size_t)MM * HH;           // 2 MB (transposed [B][H][S])
    unsigned short* Wt = Vt + (size_t)MM * HH;           // 288 KB ([192][768] bf16)

    dim3 gw(DD / 64, 3);
    wt_kernel<<<gw, 256, 0, stream>>>(Wq, Wk, Wv, Wt);

    qkv_proj_kernel<<<MM / 32, 512, 0, stream>>>(X, Wt, bq, bk, bv, Qb, Kb, Vt);

    dim3 ga(SS / 64, BB);
    attn_kernel<<<ga, 1024, 0, stream>>>(Qb, Kb, Vt, (float*)d_out);
}

// Round 4
// 95.306 us; speedup vs baseline: 9.1252x; 1.0593x over previous
//
#include <hip/hip_runtime.h>
#include <math.h>

#define BB 4
#define SS 4096
#define DD 768
#define HH 64
#define MM (BB * SS)

typedef __attribute__((ext_vector_type(8))) short bf16x8;
typedef __attribute__((ext_vector_type(4))) float f32x4;

__device__ inline unsigned short f2bf(float f) {
    union { float f; unsigned u; } x; x.f = f;
    unsigned r = x.u + 0x7fffu + ((x.u >> 16) & 1u);
    return (unsigned short)(r >> 16);
}

// ---------------- One-time weight transpose: Wq|Wk|Wv [768,64] fp32 -> Wt [192][768] bf16 ----------------
__global__ __launch_bounds__(256) void wt_kernel(
    const float* __restrict__ Wq, const float* __restrict__ Wk, const float* __restrict__ Wv,
    unsigned short* __restrict__ Wt)
{
    const int kt = blockIdx.x;
    const int sel = blockIdx.y;
    const int k0 = kt * 64;
    const float* W = (sel == 0) ? Wq : (sel == 1) ? Wk : Wv;
    __shared__ float Ws[64][68];
    const int t = threadIdx.x;
    #pragma unroll
    for (int j = 0; j < 4; ++j) {
        const int fl = t + j * 256;
        const int row = fl >> 4, c4 = (fl & 15) * 4;
        float4 v = *reinterpret_cast<const float4*>(&W[(size_t)(k0 + row) * HH + c4]);
        Ws[row][c4 + 0] = v.x; Ws[row][c4 + 1] = v.y;
        Ws[row][c4 + 2] = v.z; Ws[row][c4 + 3] = v.w;
    }
    __syncthreads();
    const int n = t >> 2;
    const int c8 = (t & 3) * 16;
    unsigned short tmp[16];
    #pragma unroll
    for (int j = 0; j < 16; ++j) tmp[j] = f2bf(Ws[c8 + j][n]);
    unsigned short* dst = &Wt[((size_t)sel * 64 + n) * DD + k0 + c8];
    *reinterpret_cast<bf16x8*>(dst)     = *reinterpret_cast<bf16x8*>(&tmp[0]);
    *reinterpret_cast<bf16x8*>(dst + 8) = *reinterpret_cast<bf16x8*>(&tmp[8]);
}

// ---------------- QKV projection via MFMA ----------------
#define PP 72
__global__ __launch_bounds__(512) void qkv_proj_kernel(
    const float* __restrict__ X, const unsigned short* __restrict__ Wt,
    const float* __restrict__ bq, const float* __restrict__ bk, const float* __restrict__ bv,
    unsigned short* __restrict__ Qb, unsigned short* __restrict__ Kb,
    unsigned short* __restrict__ Vt)
{
    __shared__ unsigned short Alds[32][PP];
    __shared__ unsigned short Blds[192][PP];

    const int tid = threadIdx.x;
    const int rowBase = blockIdx.x * 32;
    const int w = tid >> 6;
    const int ms = w & 1;
    const int nq = w >> 1;
    const int lane = tid & 63;
    const int lhi = lane >> 4, llo = lane & 15;

    f32x4 acc[3] = {{0,0,0,0},{0,0,0,0},{0,0,0,0}};

    for (int kb = 0; kb < DD / 64; ++kb) {
        const int kBase = kb * 64;
        __syncthreads();
        {
            const int row = tid >> 4, c4 = (tid & 15) * 4;
            float4 v = *reinterpret_cast<const float4*>(
                &X[(size_t)(rowBase + row) * DD + kBase + c4]);
            ushort4 pk;
            pk.x = f2bf(v.x); pk.y = f2bf(v.y); pk.z = f2bf(v.z); pk.w = f2bf(v.w);
            *reinterpret_cast<ushort4*>(&Alds[row][c4]) = pk;
        }
        #pragma unroll
        for (int i = 0; i < 3; ++i) {
            const int u = tid + i * 512;
            const int n = u >> 3, c8 = (u & 7) * 8;
            *reinterpret_cast<bf16x8*>(&Blds[n][c8]) =
                *reinterpret_cast<const bf16x8*>(&Wt[(size_t)n * DD + kBase + c8]);
        }
        __syncthreads();

        #pragma unroll
        for (int kk = 0; kk < 2; ++kk) {
            const int aoff = kk * 32 + lhi * 8;
            bf16x8 af = *reinterpret_cast<const bf16x8*>(&Alds[ms * 16 + llo][aoff]);
            #pragma unroll
            for (int nt = 0; nt < 3; ++nt) {
                bf16x8 bf = *reinterpret_cast<const bf16x8*>(&Blds[nq * 48 + nt * 16 + llo][aoff]);
                acc[nt] = __builtin_amdgcn_mfma_f32_16x16x32_bf16(af, bf, acc[nt], 0, 0, 0);
            }
        }
    }

    #pragma unroll
    for (int nt = 0; nt < 3; ++nt) {
        const int n = nq * 48 + nt * 16 + llo;
        const int sel = n >> 6;
        const int nn = n & 63;
        const float bias = (sel == 0) ? bq[nn] : (sel == 1) ? bk[nn] : bv[nn];
        #pragma unroll
        for (int r = 0; r < 4; ++r) {
            const int row = rowBase + ms * 16 + lhi * 4 + r;
            const float val = acc[nt][r] + bias;
            if (sel == 0) {
                Qb[(size_t)row * HH + nn] = f2bf(val * 0.125f);
            } else if (sel == 1) {
                Kb[(size_t)row * HH + nn] = f2bf(val);
            } else {
                const int bb = row >> 12;
                const int s = row & (SS - 1);
                Vt[((size_t)bb * HH + nn) * SS + s] = f2bf(val);
            }
        }
    }
}

// ---------------- Shared attn LDS layout ----------------
#define KP 72

union SMemA {
    struct { unsigned short K[4][64][KP]; unsigned short V[4][64][KP]; } st;
    struct { float O[3][64][68]; float ml[3][64][2]; } cb;
};

// ---------------- Split-K MFMA flash attention (balanced) ----------------
// Block = one (q-tile, key-chunk) pair. Chunk = 16 KV tiles (4 steps x 4 groups).
// Per batch: qb in [16g,16g+16) has g+1 chunks; linear block id decodes (qb, c).
// nch==1 (qb<16): write normalized output directly. Else: write (O, m, l) partial.
__global__ __launch_bounds__(1024) void attn_partial_kernel(
    const unsigned short* __restrict__ Qg, const unsigned short* __restrict__ Kg,
    const unsigned short* __restrict__ Vtg, float* __restrict__ out,
    float* __restrict__ Po, float* __restrict__ Pml)
{
    __shared__ SMemA sm;
    __shared__ unsigned short Pl[16][16][KP];

    // decode (qb, c) from linear block id
    const int l = blockIdx.x;           // 0..159
    int gg, start;
    if (l < 16)      { gg = 0; start = 0; }
    else if (l < 48) { gg = 1; start = 16; }
    else if (l < 96) { gg = 2; start = 48; }
    else             { gg = 3; start = 96; }
    const int r_ = l - start;
    const int qb = 16 * gg + r_ / (gg + 1);
    const int c  = r_ % (gg + 1);

    const int tid = threadIdx.x;
    const int b  = blockIdx.y;
    const int q0 = qb * 64;
    const int w   = tid >> 6;
    const int g   = w >> 2;
    const int wq  = w & 3;
    const int lane = tid & 63;
    const int lhi = lane >> 4, llo = lane & 15;
    const int qw0 = q0 + wq * 16;

    const int ntiles = qb + 1;
    const int base0 = c * 16;
    const int endT = min(base0 + 16, ntiles);
    const int nsteps = (endT - base0 + 3) >> 2;
    const int nch = qb / 16 + 1;

    const unsigned short* Kbase = Kg  + (size_t)b * SS * HH;
    const unsigned short* Vbase = Vtg + (size_t)b * HH * SS;

    bf16x8 qf0, qf1;
    {
        const unsigned short* qrow = Qg + ((size_t)b * SS + qw0 + llo) * HH + lhi * 8;
        qf0 = *reinterpret_cast<const bf16x8*>(qrow);
        qf1 = *reinterpret_cast<const bf16x8*>(qrow + 32);
    }

    float m[4] = {-INFINITY, -INFINITY, -INFINITY, -INFINITY};
    float lsum[4] = {0.f, 0.f, 0.f, 0.f};
    f32x4 acc_o[4] = {{0,0,0,0},{0,0,0,0},{0,0,0,0},{0,0,0,0}};

    for (int stp = 0; stp < nsteps; ++stp) {
        const int base = base0 + stp * 4;
        __syncthreads();
        #pragma unroll
        for (int i = 0; i < 4; ++i) {
            const int u = tid + i * 1024;
            const int selv = u >> 9;
            const int gi = selv & 3;
            const int t = base + gi;
            if (t < endT) {
                const int within = u & 511;
                const int row = within >> 3, c8 = (within & 7) * 8;
                if (selv < 4) {
                    *reinterpret_cast<bf16x8*>(&sm.st.K[gi][row][c8]) =
                        *reinterpret_cast<const bf16x8*>(&Kbase[(size_t)(t * 64 + row) * HH + c8]);
                } else {
                    *reinterpret_cast<bf16x8*>(&sm.st.V[gi][row][c8]) =
                        *reinterpret_cast<const bf16x8*>(&Vbase[(size_t)row * SS + t * 64 + c8]);
                }
            }
        }
        __syncthreads();

        const int lt = base + g;
        if (lt < endT) {
            const int k0 = lt * 64;
            const unsigned short (&Ks)[64][KP] = sm.st.K[g];
            const unsigned short (&Vs)[64][KP] = sm.st.V[g];

            f32x4 sacc[4] = {{0,0,0,0},{0,0,0,0},{0,0,0,0},{0,0,0,0}};
            #pragma unroll
            for (int kt = 0; kt < 4; ++kt) {
                bf16x8 kfa = *reinterpret_cast<const bf16x8*>(&Ks[kt * 16 + llo][lhi * 8]);
                bf16x8 kfb = *reinterpret_cast<const bf16x8*>(&Ks[kt * 16 + llo][32 + lhi * 8]);
                sacc[kt] = __builtin_amdgcn_mfma_f32_16x16x32_bf16(qf0, kfa, sacc[kt], 0, 0, 0);
                sacc[kt] = __builtin_amdgcn_mfma_f32_16x16x32_bf16(qf1, kfb, sacc[kt], 0, 0, 0);
            }

            if (k0 + 63 > qw0) {
                #pragma unroll
                for (int kt = 0; kt < 4; ++kt) {
                    const int k = k0 + kt * 16 + llo;
                    #pragma unroll
                    for (int r = 0; r < 4; ++r) {
                        const int q = qw0 + lhi * 4 + r;
                        if (k > q) sacc[kt][r] = -INFINITY;
                    }
                }
            }

            float p[4][4];
            #pragma unroll
            for (int r = 0; r < 4; ++r) {
                float mx = fmaxf(fmaxf(sacc[0][r], sacc[1][r]), fmaxf(sacc[2][r], sacc[3][r]));
                mx = fmaxf(mx, __shfl_xor(mx, 1));
                mx = fmaxf(mx, __shfl_xor(mx, 2));
                mx = fmaxf(mx, __shfl_xor(mx, 4));
                mx = fmaxf(mx, __shfl_xor(mx, 8));
                const float mn = fmaxf(m[r], mx);
                const float corr = __expf(m[r] - mn);
                float ps = 0.f;
                #pragma unroll
                for (int kt = 0; kt < 4; ++kt) { p[kt][r] = __expf(sacc[kt][r] - mn); ps += p[kt][r]; }
                ps += __shfl_xor(ps, 1);
                ps += __shfl_xor(ps, 2);
                ps += __shfl_xor(ps, 4);
                ps += __shfl_xor(ps, 8);
                lsum[r] = lsum[r] * corr + ps;
                m[r] = mn;
                #pragma unroll
                for (int dt = 0; dt < 4; ++dt) acc_o[dt][r] *= corr;
            }

            #pragma unroll
            for (int kt = 0; kt < 4; ++kt)
                #pragma unroll
                for (int r = 0; r < 4; ++r)
                    Pl[w][lhi * 4 + r][kt * 16 + llo] = f2bf(p[kt][r]);

            bf16x8 pf0 = *reinterpret_cast<const bf16x8*>(&Pl[w][llo][lhi * 8]);
            bf16x8 pf1 = *reinterpret_cast<const bf16x8*>(&Pl[w][llo][32 + lhi * 8]);

            #pragma unroll
            for (int dt = 0; dt < 4; ++dt) {
                bf16x8 vfa = *reinterpret_cast<const bf16x8*>(&Vs[dt * 16 + llo][lhi * 8]);
                bf16x8 vfb = *reinterpret_cast<const bf16x8*>(&Vs[dt * 16 + llo][32 + lhi * 8]);
                acc_o[dt] = __builtin_amdgcn_mfma_f32_16x16x32_bf16(pf0, vfa, acc_o[dt], 0, 0, 0);
                acc_o[dt] = __builtin_amdgcn_mfma_f32_16x16x32_bf16(pf1, vfb, acc_o[dt], 0, 0, 0);
            }
        }
    }

    // ---- 4-way in-block flash combine ----
    __syncthreads();
    if (g > 0) {
        #pragma unroll
        for (int dt = 0; dt < 4; ++dt)
            #pragma unroll
            for (int r = 0; r < 4; ++r)
                sm.cb.O[g - 1][wq * 16 + lhi * 4 + r][dt * 16 + llo] = acc_o[dt][r];
        if (llo == 0) {
            #pragma unroll
            for (int r = 0; r < 4; ++r) {
                sm.cb.ml[g - 1][wq * 16 + lhi * 4 + r][0] = m[r];
                sm.cb.ml[g - 1][wq * 16 + lhi * 4 + r][1] = lsum[r];
            }
        }
    }
    __syncthreads();
    if (g == 0) {
        float* PoT  = Po  + (((size_t)(b * 64 + qb) * 4 + c) << 12);
        float* PmlT = Pml + (((size_t)(b * 64 + qb) * 4 + c) << 7);
        #pragma unroll
        for (int r = 0; r < 4; ++r) {
            const int row = wq * 16 + lhi * 4 + r;
            float mg[3], lg[3];
            #pragma unroll
            for (int j = 0; j < 3; ++j) { mg[j] = sm.cb.ml[j][row][0]; lg[j] = sm.cb.ml[j][row][1]; }
            float M = fmaxf(fmaxf(m[r], mg[0]), fmaxf(mg[1], mg[2]));
            const float a0 = __expf(m[r] - M);
            float ag[3];
            float L = lsum[r] * a0;
            #pragma unroll
            for (int j = 0; j < 3; ++j) { ag[j] = __expf(mg[j] - M); L += lg[j] * ag[j]; }
            if (nch == 1) {
                const float invL = 1.f / L;
                const size_t orow = ((size_t)b * SS + q0 + row) * HH;
                #pragma unroll
                for (int dt = 0; dt < 4; ++dt) {
                    float o = acc_o[dt][r] * a0;
                    #pragma unroll
                    for (int j = 0; j < 3; ++j) o += sm.cb.O[j][row][dt * 16 + llo] * ag[j];
                    out[orow + dt * 16 + llo] = o * invL;
                }
            } else {
                #pragma unroll
                for (int dt = 0; dt < 4; ++dt) {
                    float o = acc_o[dt][r] * a0;
                    #pragma unroll
                    for (int j = 0; j < 3; ++j) o += sm.cb.O[j][row][dt * 16 + llo] * ag[j];
                    PoT[row * 64 + dt * 16 + llo] = o;
                }
                if (llo == 0) { PmlT[row] = M; PmlT[64 + row] = L; }
            }
        }
    }
}

// ---------------- Partial combine: q-tiles 16..63 (2..4 chunks each) ----------------
__global__ __launch_bounds__(256) void combine_kernel(
    const float* __restrict__ Po, const float* __restrict__ Pml, float* __restrict__ out)
{
    const int qt = 16 + blockIdx.x;
    const int b  = blockIdx.y;
    const int nch = qt / 16 + 1;
    const int t = threadIdx.x;
    const int row = t >> 2;
    const int col0 = (t & 3) * 16;
    const size_t baseIdx = (size_t)(b * 64 + qt) * 4;

    float mv[4], lv[4], a[4];
    float M = -INFINITY;
    for (int cc = 0; cc < nch; ++cc) {
        const float* PmlT = Pml + ((baseIdx + cc) << 7);
        mv[cc] = PmlT[row];
        lv[cc] = PmlT[64 + row];
        M = fmaxf(M, mv[cc]);
    }
    float L = 0.f;
    for (int cc = 0; cc < nch; ++cc) { a[cc] = __expf(mv[cc] - M); L += a[cc] * lv[cc]; }
    const float invL = 1.f / L;

    #pragma unroll
    for (int j = 0; j < 4; ++j) {
        float4 s = {0.f, 0.f, 0.f, 0.f};
        for (int cc = 0; cc < nch; ++cc) {
            const float4 v = *reinterpret_cast<const float4*>(
                &Po[((baseIdx + cc) << 12) + row * 64 + col0 + j * 4]);
            s.x += a[cc] * v.x; s.y += a[cc] * v.y;
            s.z += a[cc] * v.z; s.w += a[cc] * v.w;
        }
        s.x *= invL; s.y *= invL; s.z *= invL; s.w *= invL;
        *reinterpret_cast<float4*>(&out[((size_t)b * SS + qt * 64 + row) * HH + col0 + j * 4]) = s;
    }
}

// ---------------- Fallback: verified R3 attention (used if ws too small) ----------------
__global__ __launch_bounds__(1024) void attn_kernel(
    const unsigned short* __restrict__ Qg, const unsigned short* __restrict__ Kg,
    const unsigned short* __restrict__ Vtg, float* __restrict__ out)
{
    __shared__ SMemA sm;
    __shared__ unsigned short Pl[16][16][KP];

    const int tid = threadIdx.x;
    const int b  = blockIdx.y;
    const int qb = blockIdx.x;
    const int q0 = qb * 64;
    const int w   = tid >> 6;
    const int g   = w >> 2;
    const int wq  = w & 3;
    const int lane = tid & 63;
    const int lhi = lane >> 4, llo = lane & 15;
    const int qw0 = q0 + wq * 16;

    const unsigned short* Kbase = Kg  + (size_t)b * SS * HH;
    const unsigned short* Vbase = Vtg + (size_t)b * HH * SS;

    bf16x8 qf0, qf1;
    {
        const unsigned short* qrow = Qg + ((size_t)b * SS + qw0 + llo) * HH + lhi * 8;
        qf0 = *reinterpret_cast<const bf16x8*>(qrow);
        qf1 = *reinterpret_cast<const bf16x8*>(qrow + 32);
    }

    float m[4] = {-INFINITY, -INFINITY, -INFINITY, -INFINITY};
    float lsum[4] = {0.f, 0.f, 0.f, 0.f};
    f32x4 acc_o[4] = {{0,0,0,0},{0,0,0,0},{0,0,0,0},{0,0,0,0}};

    const int ntiles = qb + 1;
    const int nsteps = (ntiles + 3) >> 2;

    for (int stp = 0; stp < nsteps; ++stp) {
        const int base = stp * 4;
        __syncthreads();
        #pragma unroll
        for (int i = 0; i < 4; ++i) {
            const int u = tid + i * 1024;
            const int selv = u >> 9;
            const int gi = selv & 3;
            const int t = base + gi;
            if (t < ntiles) {
                const int within = u & 511;
                const int row = within >> 3, c8 = (within & 7) * 8;
                if (selv < 4) {
                    *reinterpret_cast<bf16x8*>(&sm.st.K[gi][row][c8]) =
                        *reinterpret_cast<const bf16x8*>(&Kbase[(size_t)(t * 64 + row) * HH + c8]);
                } else {
                    *reinterpret_cast<bf16x8*>(&sm.st.V[gi][row][c8]) =
                        *reinterpret_cast<const bf16x8*>(&Vbase[(size_t)row * SS + t * 64 + c8]);
                }
            }
        }
        __syncthreads();

        const int lt = base + g;
        if (lt < ntiles) {
            const int k0 = lt * 64;
            const unsigned short (&Ks)[64][KP] = sm.st.K[g];
            const unsigned short (&Vs)[64][KP] = sm.st.V[g];

            f32x4 sacc[4] = {{0,0,0,0},{0,0,0,0},{0,0,0,0},{0,0,0,0}};
            #pragma unroll
            for (int kt = 0; kt < 4; ++kt) {
                bf16x8 kfa = *reinterpret_cast<const bf16x8*>(&Ks[kt * 16 + llo][lhi * 8]);
                bf16x8 kfb = *reinterpret_cast<const bf16x8*>(&Ks[kt * 16 + llo][32 + lhi * 8]);
                sacc[kt] = __builtin_amdgcn_mfma_f32_16x16x32_bf16(qf0, kfa, sacc[kt], 0, 0, 0);
                sacc[kt] = __builtin_amdgcn_mfma_f32_16x16x32_bf16(qf1, kfb, sacc[kt], 0, 0, 0);
            }

            if (k0 + 63 > qw0) {
                #pragma unroll
                for (int kt = 0; kt < 4; ++kt) {
                    const int k = k0 + kt * 16 + llo;
                    #pragma unroll
                    for (int r = 0; r < 4; ++r) {
                        const int q = qw0 + lhi * 4 + r;
                        if (k > q) sacc[kt][r] = -INFINITY;
                    }
                }
            }

            float p[4][4];
            #pragma unroll
            for (int r = 0; r < 4; ++r) {
                float mx = fmaxf(fmaxf(sacc[0][r], sacc[1][r]), fmaxf(sacc[2][r], sacc[3][r]));
                mx = fmaxf(mx, __shfl_xor(mx, 1));
                mx = fmaxf(mx, __shfl_xor(mx, 2));
                mx = fmaxf(mx, __shfl_xor(mx, 4));
                mx = fmaxf(mx, __shfl_xor(mx, 8));
                const float mn = fmaxf(m[r], mx);
                const float corr = __expf(m[r] - mn);
                float ps = 0.f;
                #pragma unroll
                for (int kt = 0; kt < 4; ++kt) { p[kt][r] = __expf(sacc[kt][r] - mn); ps += p[kt][r]; }
                ps += __shfl_xor(ps, 1);
                ps += __shfl_xor(ps, 2);
                ps += __shfl_xor(ps, 4);
                ps += __shfl_xor(ps, 8);
                lsum[r] = lsum[r] * corr + ps;
                m[r] = mn;
                #pragma unroll
                for (int dt = 0; dt < 4; ++dt) acc_o[dt][r] *= corr;
            }

            #pragma unroll
            for (int kt = 0; kt < 4; ++kt)
                #pragma unroll
                for (int r = 0; r < 4; ++r)
                    Pl[w][lhi * 4 + r][kt * 16 + llo] = f2bf(p[kt][r]);

            bf16x8 pf0 = *reinterpret_cast<const bf16x8*>(&Pl[w][llo][lhi * 8]);
            bf16x8 pf1 = *reinterpret_cast<const bf16x8*>(&Pl[w][llo][32 + lhi * 8]);

            #pragma unroll
            for (int dt = 0; dt < 4; ++dt) {
                bf16x8 vfa = *reinterpret_cast<const bf16x8*>(&Vs[dt * 16 + llo][lhi * 8]);
                bf16x8 vfb = *reinterpret_cast<const bf16x8*>(&Vs[dt * 16 + llo][32 + lhi * 8]);
                acc_o[dt] = __builtin_amdgcn_mfma_f32_16x16x32_bf16(pf0, vfa, acc_o[dt], 0, 0, 0);
                acc_o[dt] = __builtin_amdgcn_mfma_f32_16x16x32_bf16(pf1, vfb, acc_o[dt], 0, 0, 0);
            }
        }
    }

    __syncthreads();
    if (g > 0) {
        #pragma unroll
        for (int dt = 0; dt < 4; ++dt)
            #pragma unroll
            for (int r = 0; r < 4; ++r)
                sm.cb.O[g - 1][wq * 16 + lhi * 4 + r][dt * 16 + llo] = acc_o[dt][r];
        if (llo == 0) {
            #pragma unroll
            for (int r = 0; r < 4; ++r) {
                sm.cb.ml[g - 1][wq * 16 + lhi * 4 + r][0] = m[r];
                sm.cb.ml[g - 1][wq * 16 + lhi * 4 + r][1] = lsum[r];
            }
        }
    }
    __syncthreads();
    if (g == 0) {
        #pragma unroll
        for (int r = 0; r < 4; ++r) {
            const int row = wq * 16 + lhi * 4 + r;
            float mg[3], lg[3];
            #pragma unroll
            for (int j = 0; j < 3; ++j) { mg[j] = sm.cb.ml[j][row][0]; lg[j] = sm.cb.ml[j][row][1]; }
            float M = fmaxf(fmaxf(m[r], mg[0]), fmaxf(mg[1], mg[2]));
            const float a0 = __expf(m[r] - M);
            float ag[3];
            float L = lsum[r] * a0;
            #pragma unroll
            for (int j = 0; j < 3; ++j) { ag[j] = __expf(mg[j] - M); L += lg[j] * ag[j]; }
            const float invL = 1.f / L;
            const size_t orow = ((size_t)b * SS + q0 + row) * HH;
            #pragma unroll
            for (int dt = 0; dt < 4; ++dt) {
                float o = acc_o[dt][r] * a0;
                #pragma unroll
                for (int j = 0; j < 3; ++j) o += sm.cb.O[j][row][dt * 16 + llo] * ag[j];
                out[orow + dt * 16 + llo] = o * invL;
            }
        }
    }
}

extern "C" void kernel_launch(void* const* d_in, const int* in_sizes, int n_in,
                              void* d_out, int out_size, void* d_ws, size_t ws_size,
                              hipStream_t stream)
{
    const float* X  = (const float*)d_in[0];
    const float* Wq = (const float*)d_in[1];
    const float* bq = (const float*)d_in[2];
    const float* Wk = (const float*)d_in[3];
    const float* bk = (const float*)d_in[4];
    const float* Wv = (const float*)d_in[5];
    const float* bv = (const float*)d_in[6];

    unsigned short* Qb = (unsigned short*)d_ws;          // 2 MB
    unsigned short* Kb = Qb + (size_t)MM * HH;           // 2 MB
    unsigned short* Vt = Kb + (size_t)MM * HH;           // 2 MB (transposed [B][H][S])
    unsigned short* Wt = Vt + (size_t)MM * HH;           // 288 KB
    float* Po  = (float*)(Wt + (size_t)192 * DD);        // 16 MB  (4*64*4 tiles x 64x64 f32)
    float* Pml = Po + ((size_t)BB * 64 * 4 << 12);       // 512 KB (4*64*4 x 128 f32)

    const size_t WS_NEED = (size_t)3 * MM * HH * 2 + (size_t)192 * DD * 2
                         + ((size_t)BB * 64 * 4 << 12) * 4 + ((size_t)BB * 64 * 4 << 7) * 4;

    dim3 gw(DD / 64, 3);
    wt_kernel<<<gw, 256, 0, stream>>>(Wq, Wk, Wv, Wt);

    qkv_proj_kernel<<<MM / 32, 512, 0, stream>>>(X, Wt, bq, bk, bv, Qb, Kb, Vt);

    if (ws_size >= WS_NEED) {
        dim3 ga(160, BB);
        attn_partial_kernel<<<ga, 1024, 0, stream>>>(Qb, Kb, Vt, (float*)d_out, Po, Pml);
        dim3 gc(48, BB);
        combine_kernel<<<gc, 256, 0, stream>>>(Po, Pml, (float*)d_out);
    } else {
        dim3 ga(SS / 64, BB);
        attn_kernel<<<ga, 1024, 0, stream>>>(Qb, Kb, Vt, (float*)d_out);
    }
}